// Round 1
// baseline (219.946 us; speedup 1.0000x reference)
//
#include <hip/hip_runtime.h>

#define HW   4096
#define HIMG 64
#define WIMG 64
#define CC   256
#define CR   32

// ---------------------------------------------------------------------------
// Projection GEMM: out[o, hw] = W[o,:] . x[:, hw] + b[o], o in [0,320)
//   o <  32 -> q (Wq,bq) ; o < 64 -> k (Wk,bk) ; else -> v (Wv,bv)
// grid (HW/256, 320/16, B), 256 threads. Thread = 1 pixel, 16 out channels.
// W/b accesses are wave-uniform -> scalar loads; x loads coalesced over hw.
// ---------------------------------------------------------------------------
__global__ __launch_bounds__(256) void proj_kernel(
    const float* __restrict__ x,
    const float* __restrict__ Wq, const float* __restrict__ bq,
    const float* __restrict__ Wk, const float* __restrict__ bk,
    const float* __restrict__ Wv, const float* __restrict__ bv,
    float* __restrict__ q, float* __restrict__ k, float* __restrict__ v)
{
    const int b  = blockIdx.z;
    const int o0 = blockIdx.y * 16;                 // 0..319, chunk of 16
    const int hw = blockIdx.x * 256 + threadIdx.x;  // pixel

    const float* Wsel; const float* bsel; float* dst; int orel0; int nch;
    if (o0 < 32)      { Wsel = Wq; bsel = bq; dst = q; orel0 = o0;      nch = 32;  }
    else if (o0 < 64) { Wsel = Wk; bsel = bk; dst = k; orel0 = o0 - 32; nch = 32;  }
    else              { Wsel = Wv; bsel = bv; dst = v; orel0 = o0 - 64; nch = 256; }

    float acc[16];
    #pragma unroll
    for (int j = 0; j < 16; ++j) acc[j] = bsel[orel0 + j];

    const float* xp = x + (size_t)b * CC * HW + hw;
    const float* wp = Wsel + (size_t)orel0 * CC;

    #pragma unroll 4
    for (int c = 0; c < CC; ++c) {
        float xv = xp[(size_t)c * HW];
        #pragma unroll
        for (int j = 0; j < 16; ++j)
            acc[j] = fmaf(wp[j * CC + c], xv, acc[j]);
    }

    float* dp = dst + ((size_t)b * nch + orel0) * HW + hw;
    #pragma unroll
    for (int j = 0; j < 16; ++j) dp[(size_t)j * HW] = acc[j];
}

// ---------------------------------------------------------------------------
// Local 3x3 attention per pixel. One block per (image row h, batch b).
// unfold zero-pad semantics: OOB neighbor -> energy 0 (still in softmax),
// OOB v contribution -> 0.
// ---------------------------------------------------------------------------
__global__ __launch_bounds__(256) void attn_kernel(
    const float* __restrict__ x,
    const float* __restrict__ q_,
    const float* __restrict__ k_,
    const float* __restrict__ v_,
    const float* __restrict__ gamma,
    float* __restrict__ out)
{
    __shared__ float qs[64][33];      // [px][cr], pad 33 to dodge bank conflicts
    __shared__ float ks[3][64][33];   // [row][px][cr]
    __shared__ float es[64][9];       // energies
    __shared__ float as[64][9];       // softmax weights

    const int h = blockIdx.x;
    const int b = blockIdx.y;
    const int t = threadIdx.x;

    // stage q row (64 px x 32 cr)
    for (int idx = t; idx < 64 * 32; idx += 256) {
        int cr = idx >> 6, px = idx & 63;
        qs[px][cr] = q_[((size_t)b * CR + cr) * HW + h * WIMG + px];
    }
    // stage 3 k rows (zero OOB rows)
    for (int r = 0; r < 3; ++r) {
        int hh = h + r - 1;
        bool ok = (hh >= 0) && (hh < HIMG);
        for (int idx = t; idx < 64 * 32; idx += 256) {
            int cr = idx >> 6, px = idx & 63;
            ks[r][px][cr] = ok ? k_[((size_t)b * CR + cr) * HW + hh * WIMG + px]
                               : 0.f;
        }
    }
    __syncthreads();

    // energies: 64 px x 9 taps = 576 tasks
    for (int id = t; id < 576; id += 256) {
        int px = id / 9, kk = id - px * 9;
        int di = kk / 3, dj = kk - di * 3;
        int hh = h + di - 1, ww = px + dj - 1;
        float e = 0.f;
        if (hh >= 0 && hh < HIMG && ww >= 0 && ww < WIMG) {
            float s = 0.f;
            #pragma unroll
            for (int cr = 0; cr < CR; ++cr)
                s += qs[px][cr] * ks[di][ww][cr];
            e = s;
        }
        es[px][kk] = e;
    }
    __syncthreads();

    // softmax over 9 taps, one thread per pixel
    if (t < 64) {
        float m = es[t][0];
        #pragma unroll
        for (int kk = 1; kk < 9; ++kk) m = fmaxf(m, es[t][kk]);
        float ex[9]; float ssum = 0.f;
        #pragma unroll
        for (int kk = 0; kk < 9; ++kk) { ex[kk] = __expf(es[t][kk] - m); ssum += ex[kk]; }
        float inv = 1.f / ssum;
        #pragma unroll
        for (int kk = 0; kk < 9; ++kk) as[t][kk] = ex[kk] * inv;
    }
    __syncthreads();

    // out[c, px] = gamma * sum_kk attn[px][kk] * v[c, nbr(px,kk)] + x[c, px]
    const int px = t & 63;    // lane -> pixel: coalesced v/x/out accesses
    const int cg = t >> 6;    // 0..3 channel group
    float w[9]; int off[9];
    #pragma unroll
    for (int kk = 0; kk < 9; ++kk) {
        int di = kk / 3, dj = kk - di * 3;
        int hh = h + di - 1, ww = px + dj - 1;
        bool ok = (hh >= 0 && hh < HIMG && ww >= 0 && ww < WIMG);
        w[kk] = ok ? as[px][kk] : 0.f;
        int hc = min(max(hh, 0), HIMG - 1), wc = min(max(ww, 0), WIMG - 1);
        off[kk] = hc * WIMG + wc;
    }
    const float g = gamma[0];
    for (int c = cg; c < CC; c += 4) {
        const float* vb = v_ + ((size_t)b * CC + c) * HW;
        float acc = 0.f;
        #pragma unroll
        for (int kk = 0; kk < 9; ++kk)
            acc = fmaf(w[kk], vb[off[kk]], acc);
        size_t oidx = ((size_t)b * CC + c) * HW + h * WIMG + px;
        out[oidx] = fmaf(g, acc, x[oidx]);
    }
}

extern "C" void kernel_launch(void* const* d_in, const int* in_sizes, int n_in,
                              void* d_out, int out_size, void* d_ws, size_t ws_size,
                              hipStream_t stream)
{
    const float* x     = (const float*)d_in[0];
    const float* Wq    = (const float*)d_in[1];
    const float* bq    = (const float*)d_in[2];
    const float* Wk    = (const float*)d_in[3];
    const float* bk    = (const float*)d_in[4];
    const float* Wv    = (const float*)d_in[5];
    const float* bv    = (const float*)d_in[6];
    const float* gamma = (const float*)d_in[7];
    float* out = (float*)d_out;

    const int B = 8;
    float* q = (float*)d_ws;                    //  8*32*4096  = 1.05M floats
    float* k = q + (size_t)B * CR * HW;         //  8*32*4096
    float* v = k + (size_t)B * CR * HW;         //  8*256*4096 = 8.39M floats

    proj_kernel<<<dim3(HW / 256, 320 / 16, B), 256, 0, stream>>>(
        x, Wq, bq, Wk, bk, Wv, bv, q, k, v);
    attn_kernel<<<dim3(HIMG, B), 256, 0, stream>>>(x, q, k, v, gamma, out);
}

// Round 2
// 198.744 us; speedup vs baseline: 1.1067x; 1.1067x over previous
//
#include <hip/hip_runtime.h>

#define HW   4096
#define HIMG 64
#define WIMG 64
#define CC   256
#define CR   32

// ---------------------------------------------------------------------------
// Projection GEMM: out[o, hw] = W[o,:] . x[:, hw] + b[o], o in [0,320)
// Thread = 4 pixels (float4), 16 out channels -> 64 FMA per x-load.
// grid (HW/1024, 20, B), 256 threads.
// ---------------------------------------------------------------------------
__global__ __launch_bounds__(256) void proj_kernel(
    const float* __restrict__ x,
    const float* __restrict__ Wq, const float* __restrict__ bq,
    const float* __restrict__ Wk, const float* __restrict__ bk,
    const float* __restrict__ Wv, const float* __restrict__ bv,
    float* __restrict__ q, float* __restrict__ k, float* __restrict__ v)
{
    const int b   = blockIdx.z;
    const int o0  = blockIdx.y * 16;                        // 0..319
    const int px0 = (blockIdx.x * 256 + threadIdx.x) * 4;   // pixel group

    const float* Wsel; const float* bsel; float* dst; int orel0; int nch;
    if (o0 < 32)      { Wsel = Wq; bsel = bq; dst = q; orel0 = o0;      nch = 32;  }
    else if (o0 < 64) { Wsel = Wk; bsel = bk; dst = k; orel0 = o0 - 32; nch = 32;  }
    else              { Wsel = Wv; bsel = bv; dst = v; orel0 = o0 - 64; nch = 256; }

    float4 acc[16];
    #pragma unroll
    for (int j = 0; j < 16; ++j) {
        float bb = bsel[orel0 + j];
        acc[j] = make_float4(bb, bb, bb, bb);
    }

    const float* xp = x + (size_t)b * CC * HW + px0;
    const float* wp = Wsel + (size_t)orel0 * CC;

    #pragma unroll 2
    for (int c = 0; c < CC; ++c) {
        float4 xv = *(const float4*)(xp + (size_t)c * HW);
        #pragma unroll
        for (int j = 0; j < 16; ++j) {
            float wv = wp[j * CC + c];             // wave-uniform -> s_load
            acc[j].x = fmaf(wv, xv.x, acc[j].x);
            acc[j].y = fmaf(wv, xv.y, acc[j].y);
            acc[j].z = fmaf(wv, xv.z, acc[j].z);
            acc[j].w = fmaf(wv, xv.w, acc[j].w);
        }
    }

    float* dp = dst + ((size_t)b * nch + orel0) * HW + px0;
    #pragma unroll
    for (int j = 0; j < 16; ++j)
        *(float4*)(dp + (size_t)j * HW) = acc[j];
}

// ---------------------------------------------------------------------------
// Local 3x3 attention. Block = (h, b). Phase 1: energies+softmax (LDS q/k).
// Phase 2: v applied from LDS-staged rows, each v element loaded once.
// Zero-padded LDS implements unfold's zero-pad semantics for v for free.
// ---------------------------------------------------------------------------
struct P1S { float qs[64][36]; float ks[3][64][36]; float es[64][9]; };
struct P2S { float vs[3][64][72]; };   // [row][ch][4 zero | 64 px | 4 zero]

__global__ __launch_bounds__(256) void attn_kernel(
    const float* __restrict__ x,
    const float* __restrict__ q_,
    const float* __restrict__ k_,
    const float* __restrict__ v_,
    const float* __restrict__ gamma,
    float* __restrict__ out)
{
    __shared__ union SM { P1S p1; P2S p2; } sm;
    __shared__ float as_[64][9];

    const int h = blockIdx.x;
    const int b = blockIdx.y;
    const int t = threadIdx.x;

    // ---- Phase 1: stage q row + 3 k rows ----
    for (int idx = t; idx < 64 * 32; idx += 256) {
        int cr = idx >> 6, px = idx & 63;
        sm.p1.qs[px][cr] = q_[((size_t)b * CR + cr) * HW + h * WIMG + px];
    }
    #pragma unroll
    for (int r = 0; r < 3; ++r) {
        int hh = h + r - 1;
        bool ok = (hh >= 0) && (hh < HIMG);
        for (int idx = t; idx < 64 * 32; idx += 256) {
            int cr = idx >> 6, px = idx & 63;
            sm.p1.ks[r][px][cr] =
                ok ? k_[((size_t)b * CR + cr) * HW + hh * WIMG + px] : 0.f;
        }
    }
    __syncthreads();

    // energies: 64 px x 9 taps
    for (int id = t; id < 576; id += 256) {
        int px = id / 9, kk = id - px * 9;
        int di = kk / 3, dj = kk - di * 3;
        int hh = h + di - 1, ww = px + dj - 1;
        float e = 0.f;
        if (hh >= 0 && hh < HIMG && ww >= 0 && ww < WIMG) {
            float sx = 0.f, sy = 0.f, sz = 0.f, sw = 0.f;
            #pragma unroll
            for (int c4 = 0; c4 < 8; ++c4) {
                float4 qv = *(float4*)&sm.p1.qs[px][c4 * 4];
                float4 kv = *(float4*)&sm.p1.ks[di][ww][c4 * 4];
                sx = fmaf(qv.x, kv.x, sx); sy = fmaf(qv.y, kv.y, sy);
                sz = fmaf(qv.z, kv.z, sz); sw = fmaf(qv.w, kv.w, sw);
            }
            e = (sx + sy) + (sz + sw);
        }
        sm.p1.es[px][kk] = e;
    }
    __syncthreads();

    // softmax over 9 taps
    if (t < 64) {
        float m = sm.p1.es[t][0];
        #pragma unroll
        for (int kk = 1; kk < 9; ++kk) m = fmaxf(m, sm.p1.es[t][kk]);
        float ex[9]; float ssum = 0.f;
        #pragma unroll
        for (int kk = 0; kk < 9; ++kk) {
            ex[kk] = __expf(sm.p1.es[t][kk] - m);
            ssum += ex[kk];
        }
        float inv = 1.f / ssum;
        #pragma unroll
        for (int kk = 0; kk < 9; ++kk) as_[t][kk] = ex[kk] * inv;
    }
    __syncthreads();

    // ---- Phase 2: apply weights to v, 4 chunks of 64 channels ----
    const int px0 = (t & 15) * 4;   // 4 consecutive pixels
    const int cl  = t >> 4;         // 0..15 channel lane

    float w[4][9];
    #pragma unroll
    for (int i = 0; i < 4; ++i)
        #pragma unroll
        for (int kk = 0; kk < 9; ++kk) w[i][kk] = as_[px0 + i][kk];
    const float g = gamma[0];

    for (int chunk = 0; chunk < 4; ++chunk) {
        const int c0 = chunk * 64;
        __syncthreads();   // vs reuse across chunks (and es-union on chunk 0)

        // stage 3 v rows x 64 ch x 64 px (float4), zero OOB rows
        for (int idx = t; idx < 3072; idx += 256) {
            int p4 = idx & 15, c = (idx >> 4) & 63, r = idx >> 10;
            int hh = h + r - 1;
            float4 val = make_float4(0.f, 0.f, 0.f, 0.f);
            if (hh >= 0 && hh < HIMG)
                val = *(const float4*)&v_[((size_t)b * CC + c0 + c) * HW
                                          + hh * WIMG + p4 * 4];
            *(float4*)&sm.p2.vs[r][c][4 + p4 * 4] = val;
        }
        if (t < 192) {  // zero pads
            int r = t >> 6, c = t & 63;
            float4 z = make_float4(0.f, 0.f, 0.f, 0.f);
            *(float4*)&sm.p2.vs[r][c][0]  = z;
            *(float4*)&sm.p2.vs[r][c][68] = z;
        }
        __syncthreads();

        #pragma unroll
        for (int ci = 0; ci < 4; ++ci) {
            int c = cl + 16 * ci;
            float a0 = 0.f, a1 = 0.f, a2 = 0.f, a3 = 0.f;
            #pragma unroll
            for (int r = 0; r < 3; ++r) {
                float4 ctr = *(float4*)&sm.p2.vs[r][c][4 + px0];
                float  lft = sm.p2.vs[r][c][3 + px0];
                float  rgt = sm.p2.vs[r][c][8 + px0];
                int r3 = r * 3;
                a0 = fmaf(w[0][r3], lft,   fmaf(w[0][r3+1], ctr.x, fmaf(w[0][r3+2], ctr.y, a0)));
                a1 = fmaf(w[1][r3], ctr.x, fmaf(w[1][r3+1], ctr.y, fmaf(w[1][r3+2], ctr.z, a1)));
                a2 = fmaf(w[2][r3], ctr.y, fmaf(w[2][r3+1], ctr.z, fmaf(w[2][r3+2], ctr.w, a2)));
                a3 = fmaf(w[3][r3], ctr.z, fmaf(w[3][r3+1], ctr.w, fmaf(w[3][r3+2], rgt,  a3)));
            }
            size_t base = ((size_t)b * CC + c0 + c) * HW + h * WIMG + px0;
            float4 xa = *(const float4*)&x[base];
            float4 o;
            o.x = fmaf(g, a0, xa.x); o.y = fmaf(g, a1, xa.y);
            o.z = fmaf(g, a2, xa.z); o.w = fmaf(g, a3, xa.w);
            *(float4*)&out[base] = o;
        }
    }
}

extern "C" void kernel_launch(void* const* d_in, const int* in_sizes, int n_in,
                              void* d_out, int out_size, void* d_ws, size_t ws_size,
                              hipStream_t stream)
{
    const float* x     = (const float*)d_in[0];
    const float* Wq    = (const float*)d_in[1];
    const float* bq    = (const float*)d_in[2];
    const float* Wk    = (const float*)d_in[3];
    const float* bk    = (const float*)d_in[4];
    const float* Wv    = (const float*)d_in[5];
    const float* bv    = (const float*)d_in[6];
    const float* gamma = (const float*)d_in[7];
    float* out = (float*)d_out;

    const int B = 8;
    float* q = (float*)d_ws;
    float* k = q + (size_t)B * CR * HW;
    float* v = k + (size_t)B * CR * HW;

    proj_kernel<<<dim3(HW / 1024, 320 / 16, B), 256, 0, stream>>>(
        x, Wq, bq, Wk, bk, Wv, bv, q, k, v);
    attn_kernel<<<dim3(HIMG, B), 256, 0, stream>>>(x, q, k, v, gamma, out);
}

// Round 3
// 146.816 us; speedup vs baseline: 1.4981x; 1.3537x over previous
//
#include <hip/hip_runtime.h>

#define HW   4096
#define HIMG 64
#define WIMG 64
#define CC   256
#define CR   32
#define B_   8

typedef __attribute__((ext_vector_type(8))) short bf16x8;
typedef __attribute__((ext_vector_type(4))) float f32x4;

__device__ inline unsigned short f2bf(float f) {
    union { float f; unsigned u; } v; v.f = f;
    return (unsigned short)((v.u + 0x8000u) >> 16);   // round-half-up, err ~2^-9 rel
}

// ---------------------------------------------------------------------------
// K1: weights -> bf16, concat [Wq;Wk;Wv] into Wb[320][256]; biases into bb.
// ---------------------------------------------------------------------------
__global__ __launch_bounds__(256) void wconv(
    const float* __restrict__ Wq, const float* __restrict__ bq,
    const float* __restrict__ Wk, const float* __restrict__ bk,
    const float* __restrict__ Wv, const float* __restrict__ bv,
    unsigned short* __restrict__ Wb, float* __restrict__ bb)
{
    const int o = blockIdx.x;   // 0..319
    const float* src; const float* bsrc; int orel;
    if (o < 32)      { src = Wq; bsrc = bq; orel = o;      }
    else if (o < 64) { src = Wk; bsrc = bk; orel = o - 32; }
    else             { src = Wv; bsrc = bv; orel = o - 64; }
    Wb[o * CC + threadIdx.x] = f2bf(src[orel * CC + threadIdx.x]);
    if (threadIdx.x == 0) bb[o] = bsrc[orel];
}

// ---------------------------------------------------------------------------
// K2: x[b][c][hw] fp32 -> xt[b][hw][c] bf16 (transpose via LDS 64x64 tile).
// ---------------------------------------------------------------------------
__global__ __launch_bounds__(256) void xconv(
    const float* __restrict__ x, unsigned short* __restrict__ xt)
{
    __shared__ unsigned short tile[64 * 72];   // [px][c], pitch 72
    const int b = blockIdx.z, c0 = blockIdx.y * 64, p0 = blockIdx.x * 64;
    const int t = threadIdx.x;

    #pragma unroll
    for (int i = 0; i < 4; ++i) {
        int idx = t + 256 * i;
        int c = idx >> 4, p4 = (idx & 15) * 4;
        float4 v = *(const float4*)&x[((size_t)b * CC + c0 + c) * HW + p0 + p4];
        tile[(p4 + 0) * 72 + c] = f2bf(v.x);
        tile[(p4 + 1) * 72 + c] = f2bf(v.y);
        tile[(p4 + 2) * 72 + c] = f2bf(v.z);
        tile[(p4 + 3) * 72 + c] = f2bf(v.w);
    }
    __syncthreads();
    #pragma unroll
    for (int i = 0; i < 2; ++i) {
        int chunk = t + 256 * i;
        int p = chunk >> 3, s8 = chunk & 7;
        uint4 u = *(const uint4*)&tile[p * 72 + s8 * 8];
        *(uint4*)&xt[((size_t)b * HW + p0 + p) * CC + c0 + s8 * 8] = u;
    }
}

// ---------------------------------------------------------------------------
// K3: MFMA GEMM: {q,k,v}[o][hw] = Wb[o][:] . xt[hw][:] + bb[o]
// Block M=64 x N=128, 4 waves (each 64x32 = 4x2 tiles of 16x16), K-chunk 64.
// ---------------------------------------------------------------------------
__global__ __launch_bounds__(256) void proj_gemm(
    const unsigned short* __restrict__ Wb, const float* __restrict__ bb,
    const unsigned short* __restrict__ xt,
    float* __restrict__ q, float* __restrict__ k, float* __restrict__ vv)
{
    __shared__ unsigned short As[64 * 72];    // [o][k] pitch 72
    __shared__ unsigned short Bs[128 * 72];   // [hw][k] pitch 72
    const int b   = blockIdx.z;
    const int o0  = blockIdx.y * 64;          // 0,64,128,192,256
    const int hw0 = blockIdx.x * 128;
    const int t    = threadIdx.x;
    const int lane = t & 63, wv = t >> 6;
    const int m16  = lane & 15, quad = lane >> 4;

    f32x4 acc[4][2];
    #pragma unroll
    for (int tm = 0; tm < 4; ++tm)
        #pragma unroll
        for (int tn = 0; tn < 2; ++tn)
            acc[tm][tn] = (f32x4){0.f, 0.f, 0.f, 0.f};

    for (int kc = 0; kc < 4; ++kc) {
        const int k0 = kc * 64;
        if (kc) __syncthreads();
        #pragma unroll
        for (int i = 0; i < 2; ++i) {        // stage A: 64 rows x 64 k
            int idx = t + 256 * i, row = idx >> 3, s8 = idx & 7;
            *(uint4*)&As[row * 72 + s8 * 8] =
                *(const uint4*)&Wb[(o0 + row) * CC + k0 + s8 * 8];
        }
        #pragma unroll
        for (int i = 0; i < 4; ++i) {        // stage B: 128 rows x 64 k
            int idx = t + 256 * i, row = idx >> 3, s8 = idx & 7;
            *(uint4*)&Bs[row * 72 + s8 * 8] =
                *(const uint4*)&xt[((size_t)b * HW + hw0 + row) * CC + k0 + s8 * 8];
        }
        __syncthreads();

        #pragma unroll
        for (int ks = 0; ks < 2; ++ks) {
            bf16x8 af[4], bf[2];
            #pragma unroll
            for (int tm = 0; tm < 4; ++tm)
                af[tm] = *(const bf16x8*)&As[(tm * 16 + m16) * 72 + ks * 32 + quad * 8];
            #pragma unroll
            for (int tn = 0; tn < 2; ++tn)
                bf[tn] = *(const bf16x8*)&Bs[(wv * 32 + tn * 16 + m16) * 72 + ks * 32 + quad * 8];
            #pragma unroll
            for (int tm = 0; tm < 4; ++tm)
                #pragma unroll
                for (int tn = 0; tn < 2; ++tn)
                    acc[tm][tn] = __builtin_amdgcn_mfma_f32_16x16x32_bf16(
                        af[tm], bf[tn], acc[tm][tn], 0, 0, 0);
        }
    }

    // epilogue: D row = quad*4+reg, col = lane&15
    #pragma unroll
    for (int tm = 0; tm < 4; ++tm) {
        const int ob = o0 + tm * 16;
        float* dst; int orel, nch;
        if (ob < 32)      { dst = q;  orel = ob;      nch = CR; }
        else if (ob < 64) { dst = k;  orel = ob - 32; nch = CR; }
        else              { dst = vv; orel = ob - 64; nch = CC; }
        #pragma unroll
        for (int r = 0; r < 4; ++r) {
            const int orow = quad * 4 + r;
            const float bias = bb[ob + orow];
            const size_t rowbase = ((size_t)b * nch + orel + orow) * HW;
            #pragma unroll
            for (int tn = 0; tn < 2; ++tn) {
                int hw = hw0 + wv * 32 + tn * 16 + m16;
                dst[rowbase + hw] = acc[tm][tn][r] + bias;
            }
        }
    }
}

// ---------------------------------------------------------------------------
// K4: energies + softmax -> aw[b][hw][12] (slots 0..8 used, pitch 12)
// ---------------------------------------------------------------------------
__global__ __launch_bounds__(256) void attn_w(
    const float* __restrict__ q_, const float* __restrict__ k_,
    float* __restrict__ aw)
{
    __shared__ float qs[64][33];
    __shared__ float ks[3][64][33];
    __shared__ float es[64][9];
    const int h = blockIdx.x, b = blockIdx.y, t = threadIdx.x;

    #pragma unroll
    for (int i = 0; i < 2; ++i) {
        int idx = t + 256 * i, cr = idx >> 4, p4 = (idx & 15) * 4;
        float4 vq = *(const float4*)&q_[((size_t)b * CR + cr) * HW + h * WIMG + p4];
        qs[p4 + 0][cr] = vq.x; qs[p4 + 1][cr] = vq.y;
        qs[p4 + 2][cr] = vq.z; qs[p4 + 3][cr] = vq.w;
    }
    #pragma unroll
    for (int r = 0; r < 3; ++r) {
        int hh = h + r - 1;
        bool ok = (hh >= 0) && (hh < HIMG);
        #pragma unroll
        for (int i = 0; i < 2; ++i) {
            int idx = t + 256 * i, cr = idx >> 4, p4 = (idx & 15) * 4;
            float4 vk = make_float4(0.f, 0.f, 0.f, 0.f);
            if (ok)
                vk = *(const float4*)&k_[((size_t)b * CR + cr) * HW + hh * WIMG + p4];
            ks[r][p4 + 0][cr] = vk.x; ks[r][p4 + 1][cr] = vk.y;
            ks[r][p4 + 2][cr] = vk.z; ks[r][p4 + 3][cr] = vk.w;
        }
    }
    __syncthreads();

    for (int id = t; id < 576; id += 256) {
        int px = id / 9, kk = id - px * 9;
        int di = kk / 3, dj = kk - di * 3;
        int hh = h + di - 1, ww = px + dj - 1;
        float e = 0.f;
        if (hh >= 0 && hh < HIMG && ww >= 0 && ww < WIMG) {
            float s = 0.f;
            #pragma unroll
            for (int c = 0; c < CR; ++c) s = fmaf(qs[px][c], ks[di][ww][c], s);
            e = s;
        }
        es[px][kk] = e;
    }
    __syncthreads();

    if (t < 64) {
        float m = es[t][0];
        #pragma unroll
        for (int kk = 1; kk < 9; ++kk) m = fmaxf(m, es[t][kk]);
        float ex[9]; float ssum = 0.f;
        #pragma unroll
        for (int kk = 0; kk < 9; ++kk) { ex[kk] = __expf(es[t][kk] - m); ssum += ex[kk]; }
        float inv = 1.f / ssum;
        float* dst = &aw[((size_t)b * HW + h * WIMG + t) * 12];
        #pragma unroll
        for (int kk = 0; kk < 9; ++kk) dst[kk] = ex[kk] * inv;
    }
}

// ---------------------------------------------------------------------------
// K5: apply weights to v + residual. Block = (h, 32-ch chunk, b).
// ---------------------------------------------------------------------------
__global__ __launch_bounds__(256) void apply(
    const float* __restrict__ x, const float* __restrict__ vv,
    const float* __restrict__ aw, const float* __restrict__ gamma,
    float* __restrict__ out)
{
    __shared__ float vs[3][32][72];   // [row][ch][4 zero | 64 px | 4 zero]
    __shared__ float aws[64][12];
    const int h = blockIdx.x, cb = blockIdx.y, b = blockIdx.z, t = threadIdx.x;

    if (t < 192) {
        int px = t / 3, seg = t - px * 3;
        *(float4*)&aws[px][seg * 4] =
            *(const float4*)&aw[((size_t)b * HW + h * WIMG + px) * 12 + seg * 4];
    }
    #pragma unroll
    for (int i = 0; i < 6; ++i) {
        int idx = t + 256 * i;
        int p4 = (idx & 15) * 4, c = (idx >> 4) & 31, r = idx >> 9;
        int hh = h + r - 1;
        float4 val = make_float4(0.f, 0.f, 0.f, 0.f);
        if (hh >= 0 && hh < HIMG)
            val = *(const float4*)&vv[((size_t)b * CC + cb * 32 + c) * HW + hh * WIMG + p4];
        *(float4*)&vs[r][c][4 + p4] = val;
    }
    if (t < 96) {
        int r = t >> 5, c = t & 31;
        float4 z = make_float4(0.f, 0.f, 0.f, 0.f);
        *(float4*)&vs[r][c][0]  = z;
        *(float4*)&vs[r][c][68] = z;
    }
    __syncthreads();

    const int px0 = (t & 15) * 4;
    const int cl  = t >> 4;
    float w[4][9];
    #pragma unroll
    for (int i = 0; i < 4; ++i)
        #pragma unroll
        for (int kk = 0; kk < 9; ++kk) w[i][kk] = aws[px0 + i][kk];
    const float g = gamma[0];

    #pragma unroll
    for (int ci = 0; ci < 2; ++ci) {
        int c = cl + 16 * ci;
        float a0 = 0.f, a1 = 0.f, a2 = 0.f, a3 = 0.f;
        #pragma unroll
        for (int r = 0; r < 3; ++r) {
            float4 ctr = *(float4*)&vs[r][c][4 + px0];
            float  lft = vs[r][c][3 + px0];
            float  rgt = vs[r][c][8 + px0];
            int r3 = r * 3;
            a0 = fmaf(w[0][r3], lft,   fmaf(w[0][r3+1], ctr.x, fmaf(w[0][r3+2], ctr.y, a0)));
            a1 = fmaf(w[1][r3], ctr.x, fmaf(w[1][r3+1], ctr.y, fmaf(w[1][r3+2], ctr.z, a1)));
            a2 = fmaf(w[2][r3], ctr.y, fmaf(w[2][r3+1], ctr.z, fmaf(w[2][r3+2], ctr.w, a2)));
            a3 = fmaf(w[3][r3], ctr.z, fmaf(w[3][r3+1], ctr.w, fmaf(w[3][r3+2], rgt,  a3)));
        }
        size_t base = ((size_t)b * CC + cb * 32 + c) * HW + h * WIMG + px0;
        float4 xa = *(const float4*)&x[base];
        float4 o;
        o.x = fmaf(g, a0, xa.x); o.y = fmaf(g, a1, xa.y);
        o.z = fmaf(g, a2, xa.z); o.w = fmaf(g, a3, xa.w);
        *(float4*)&out[base] = o;
    }
}

extern "C" void kernel_launch(void* const* d_in, const int* in_sizes, int n_in,
                              void* d_out, int out_size, void* d_ws, size_t ws_size,
                              hipStream_t stream)
{
    const float* x     = (const float*)d_in[0];
    const float* Wq    = (const float*)d_in[1];
    const float* bq    = (const float*)d_in[2];
    const float* Wk    = (const float*)d_in[3];
    const float* bk    = (const float*)d_in[4];
    const float* Wv    = (const float*)d_in[5];
    const float* bv    = (const float*)d_in[6];
    const float* gamma = (const float*)d_in[7];
    float* out = (float*)d_out;

    unsigned short* xt = (unsigned short*)d_ws;                    // 16.78 MB
    float* q  = (float*)((char*)d_ws + (size_t)B_ * HW * CC * 2);  //  4.19 MB
    float* k  = q  + (size_t)B_ * CR * HW;                         //  4.19 MB
    float* v  = k  + (size_t)B_ * CR * HW;                         // 33.55 MB
    float* aw = v  + (size_t)B_ * CC * HW;                         //  1.57 MB
    unsigned short* Wb = (unsigned short*)(aw + (size_t)B_ * HW * 12); // 160 KB
    float* bb = (float*)(Wb + 320 * CC);                           // 1.3 KB

    wconv<<<dim3(320), 256, 0, stream>>>(Wq, bq, Wk, bk, Wv, bv, Wb, bb);
    xconv<<<dim3(HW / 64, CC / 64, B_), 256, 0, stream>>>(x, xt);
    proj_gemm<<<dim3(HW / 128, 320 / 64, B_), 256, 0, stream>>>(Wb, bb, xt, q, k, v);
    attn_w<<<dim3(HIMG, B_), 256, 0, stream>>>(q, k, aw);
    apply<<<dim3(HIMG, CC / 32, B_), 256, 0, stream>>>(x, v, aw, gamma, out);
}

// Round 4
// 134.144 us; speedup vs baseline: 1.6396x; 1.0945x over previous
//
#include <hip/hip_runtime.h>

#define HW   4096
#define HIMG 64
#define WIMG 64
#define CC   256
#define CR   32
#define B_   8

typedef __attribute__((ext_vector_type(8))) short bf16x8;
typedef __attribute__((ext_vector_type(4))) float f32x4;

__device__ inline unsigned short f2bf(float f) {
    union { float f; unsigned u; } v; v.f = f;
    return (unsigned short)((v.u + 0x8000u) >> 16);
}
__device__ inline float bf2f(unsigned short h) {
    union { unsigned u; float f; } v; v.u = ((unsigned)h) << 16; return v.f;
}
__device__ inline unsigned pack2(float a, float b) {
    return (unsigned)f2bf(a) | ((unsigned)f2bf(b) << 16);
}

// ---------------------------------------------------------------------------
// K1: weights -> bf16, concat [Wq;Wk;Wv] into Wb[320][256]; biases into bb.
// ---------------------------------------------------------------------------
__global__ __launch_bounds__(256) void wconv(
    const float* __restrict__ Wq, const float* __restrict__ bq,
    const float* __restrict__ Wk, const float* __restrict__ bk,
    const float* __restrict__ Wv, const float* __restrict__ bv,
    unsigned short* __restrict__ Wb, float* __restrict__ bb)
{
    const int o = blockIdx.x;   // 0..319
    const float* src; const float* bsrc; int orel;
    if (o < 32)      { src = Wq; bsrc = bq; orel = o;      }
    else if (o < 64) { src = Wk; bsrc = bk; orel = o - 32; }
    else             { src = Wv; bsrc = bv; orel = o - 64; }
    Wb[o * CC + threadIdx.x] = f2bf(src[orel * CC + threadIdx.x]);
    if (threadIdx.x == 0) bb[o] = bsrc[orel];
}

// ---------------------------------------------------------------------------
// K2: fused transpose+convert+GEMM.
// Block: M=320 (all out channels) x N=64 px, K=256 in 4 chunks of 64.
// x read from HBM exactly once. Wave wv: m-tiles [5wv,5wv+5) x all 4 n-tiles.
// LDS: As bf16 [320][72]; xt32 fp32 [64][65] (transpose buf);
//      Bs bf16 [px][64] with XOR-swizzled 8-elem groups (conflict-free b128).
// ---------------------------------------------------------------------------
__global__ __launch_bounds__(256) void proj_gemm(
    const unsigned short* __restrict__ Wb, const float* __restrict__ bb,
    const float* __restrict__ x,
    float* __restrict__ q, float* __restrict__ k,
    unsigned short* __restrict__ vv)
{
    __shared__ unsigned short As[320 * 72];
    __shared__ float          xt32[64 * 65];
    __shared__ unsigned short Bs[64 * 64];

    const int b   = blockIdx.y;
    const int hw0 = blockIdx.x * 64;
    const int t    = threadIdx.x;
    const int lane = t & 63, wv = t >> 6;
    const int m16  = lane & 15, quad = lane >> 4;

    f32x4 acc[5][4];
    #pragma unroll
    for (int i = 0; i < 5; ++i)
        #pragma unroll
        for (int n = 0; n < 4; ++n)
            acc[i][n] = (f32x4){0.f, 0.f, 0.f, 0.f};

    for (int kc = 0; kc < 4; ++kc) {
        const int k0 = kc * 64;
        if (kc) __syncthreads();            // protect As/xt32/Bs reuse

        // stage A: 320 rows x 64 k bf16 (L2-resident W)
        #pragma unroll
        for (int i = 0; i < 10; ++i) {
            int idx = t + 256 * i;          // 0..2559
            int row = idx >> 3, s8 = idx & 7;
            *(uint4*)&As[row * 72 + s8 * 8] =
                *(const uint4*)&Wb[row * CC + k0 + s8 * 8];
        }
        // stage x chunk fp32: 64 c x 64 px, coalesced along px
        #pragma unroll
        for (int i = 0; i < 4; ++i) {
            int idx = t + 256 * i;          // 0..1023
            int c = idx >> 4, p4 = (idx & 15) * 4;
            float4 vx = *(const float4*)&x[((size_t)b * CC + k0 + c) * HW + hw0 + p4];
            *(float4*)&xt32[c * 65 + p4] = vx;
        }
        __syncthreads();

        // transpose+convert into Bs: thread -> px = lane, 16 channels
        {
            const int px = lane;
            const int c0 = wv * 16;
            float f[16];
            #pragma unroll
            for (int j = 0; j < 16; ++j)
                f[j] = xt32[(c0 + j) * 65 + px];   // bank (c0+j+px)%32: 2-way
            uint4 w0, w1;
            w0.x = pack2(f[0],  f[1]);  w0.y = pack2(f[2],  f[3]);
            w0.z = pack2(f[4],  f[5]);  w0.w = pack2(f[6],  f[7]);
            w1.x = pack2(f[8],  f[9]);  w1.y = pack2(f[10], f[11]);
            w1.z = pack2(f[12], f[13]); w1.w = pack2(f[14], f[15]);
            const int lg0 = c0 >> 3, sw = px & 7;
            *(uint4*)&Bs[px * 64 + ((lg0     ^ sw) * 8)] = w0;
            *(uint4*)&Bs[px * 64 + (((lg0+1) ^ sw) * 8)] = w1;
        }
        __syncthreads();

        #pragma unroll
        for (int ks = 0; ks < 2; ++ks) {
            bf16x8 af[5], bf[4];
            #pragma unroll
            for (int i = 0; i < 5; ++i)
                af[i] = *(const bf16x8*)&As[((wv * 5 + i) * 16 + m16) * 72
                                            + ks * 32 + quad * 8];
            #pragma unroll
            for (int n = 0; n < 4; ++n) {
                int px = n * 16 + m16;
                int lg = ks * 4 + quad;
                bf[n] = *(const bf16x8*)&Bs[px * 64 + ((lg ^ (px & 7)) * 8)];
            }
            #pragma unroll
            for (int i = 0; i < 5; ++i)
                #pragma unroll
                for (int n = 0; n < 4; ++n)
                    acc[i][n] = __builtin_amdgcn_mfma_f32_16x16x32_bf16(
                        af[i], bf[n], acc[i][n], 0, 0, 0);
        }
    }

    // epilogue: D row = quad*4+reg, col = lane&15
    #pragma unroll
    for (int i = 0; i < 5; ++i) {
        const int ob = (wv * 5 + i) * 16;        // 0..304, wave-uniform
        #pragma unroll
        for (int r = 0; r < 4; ++r) {
            const int orow = quad * 4 + r;
            const float bias = bb[ob + orow];
            if (ob < 64) {                        // q or k, fp32
                float* dst = (ob < 32) ? q : k;
                int orel = (ob < 32) ? ob : ob - 32;
                size_t rowbase = ((size_t)b * CR + orel + orow) * HW;
                #pragma unroll
                for (int n = 0; n < 4; ++n)
                    dst[rowbase + hw0 + n * 16 + m16] = acc[i][n][r] + bias;
            } else {                              // v, bf16
                size_t rowbase = ((size_t)b * CC + (ob - 64) + orow) * HW;
                #pragma unroll
                for (int n = 0; n < 4; ++n)
                    vv[rowbase + hw0 + n * 16 + m16] = f2bf(acc[i][n][r] + bias);
            }
        }
    }
}

// ---------------------------------------------------------------------------
// K3: energies + softmax -> aw[b][hw][12]
// ---------------------------------------------------------------------------
__global__ __launch_bounds__(256) void attn_w(
    const float* __restrict__ q_, const float* __restrict__ k_,
    float* __restrict__ aw)
{
    __shared__ float qs[64][33];
    __shared__ float ks[3][64][33];
    __shared__ float es[64][9];
    const int h = blockIdx.x, b = blockIdx.y, t = threadIdx.x;

    #pragma unroll
    for (int i = 0; i < 2; ++i) {
        int idx = t + 256 * i, cr = idx >> 4, p4 = (idx & 15) * 4;
        float4 vq = *(const float4*)&q_[((size_t)b * CR + cr) * HW + h * WIMG + p4];
        qs[p4 + 0][cr] = vq.x; qs[p4 + 1][cr] = vq.y;
        qs[p4 + 2][cr] = vq.z; qs[p4 + 3][cr] = vq.w;
    }
    #pragma unroll
    for (int r = 0; r < 3; ++r) {
        int hh = h + r - 1;
        bool ok = (hh >= 0) && (hh < HIMG);
        #pragma unroll
        for (int i = 0; i < 2; ++i) {
            int idx = t + 256 * i, cr = idx >> 4, p4 = (idx & 15) * 4;
            float4 vk = make_float4(0.f, 0.f, 0.f, 0.f);
            if (ok)
                vk = *(const float4*)&k_[((size_t)b * CR + cr) * HW + hh * WIMG + p4];
            ks[r][p4 + 0][cr] = vk.x; ks[r][p4 + 1][cr] = vk.y;
            ks[r][p4 + 2][cr] = vk.z; ks[r][p4 + 3][cr] = vk.w;
        }
    }
    __syncthreads();

    for (int id = t; id < 576; id += 256) {
        int px = id / 9, kk = id - px * 9;
        int di = kk / 3, dj = kk - di * 3;
        int hh = h + di - 1, ww = px + dj - 1;
        float e = 0.f;
        if (hh >= 0 && hh < HIMG && ww >= 0 && ww < WIMG) {
            float s = 0.f;
            #pragma unroll
            for (int c = 0; c < CR; ++c) s = fmaf(qs[px][c], ks[di][ww][c], s);
            e = s;
        }
        es[px][kk] = e;
    }
    __syncthreads();

    if (t < 64) {
        float m = es[t][0];
        #pragma unroll
        for (int kk = 1; kk < 9; ++kk) m = fmaxf(m, es[t][kk]);
        float ex[9]; float ssum = 0.f;
        #pragma unroll
        for (int kk = 0; kk < 9; ++kk) { ex[kk] = __expf(es[t][kk] - m); ssum += ex[kk]; }
        float inv = 1.f / ssum;
        float* dst = &aw[((size_t)b * HW + h * WIMG + t) * 12];
        #pragma unroll
        for (int kk = 0; kk < 9; ++kk) dst[kk] = ex[kk] * inv;
    }
}

// ---------------------------------------------------------------------------
// K4: apply weights to v (bf16) + residual. Block = (h, 32-ch chunk, b).
// ---------------------------------------------------------------------------
__global__ __launch_bounds__(256) void apply(
    const float* __restrict__ x, const unsigned short* __restrict__ vv,
    const float* __restrict__ aw, const float* __restrict__ gamma,
    float* __restrict__ out)
{
    __shared__ float vs[3][32][72];   // [row][ch][4 zero | 64 px | 4 zero]
    __shared__ float aws[64][12];
    const int h = blockIdx.x, cb = blockIdx.y, b = blockIdx.z, t = threadIdx.x;

    if (t < 192) {
        int px = t / 3, seg = t - px * 3;
        *(float4*)&aws[px][seg * 4] =
            *(const float4*)&aw[((size_t)b * HW + h * WIMG + px) * 12 + seg * 4];
    }
    #pragma unroll
    for (int i = 0; i < 6; ++i) {
        int idx = t + 256 * i;          // 0..1535
        int p4 = (idx & 15) * 4, c = (idx >> 4) & 31, r = idx >> 9;
        int hh = h + r - 1;
        float4 val = make_float4(0.f, 0.f, 0.f, 0.f);
        if (hh >= 0 && hh < HIMG) {
            ushort4 u = *(const ushort4*)&vv[((size_t)b * CC + cb * 32 + c) * HW
                                             + hh * WIMG + p4];
            val = make_float4(bf2f(u.x), bf2f(u.y), bf2f(u.z), bf2f(u.w));
        }
        *(float4*)&vs[r][c][4 + p4] = val;
    }
    if (t < 96) {
        int r = t >> 5, c = t & 31;
        float4 z = make_float4(0.f, 0.f, 0.f, 0.f);
        *(float4*)&vs[r][c][0]  = z;
        *(float4*)&vs[r][c][68] = z;
    }
    __syncthreads();

    const int px0 = (t & 15) * 4;
    const int cl  = t >> 4;
    float w[4][9];
    #pragma unroll
    for (int i = 0; i < 4; ++i)
        #pragma unroll
        for (int kk = 0; kk < 9; ++kk) w[i][kk] = aws[px0 + i][kk];
    const float g = gamma[0];

    #pragma unroll
    for (int ci = 0; ci < 2; ++ci) {
        int c = cl + 16 * ci;
        float a0 = 0.f, a1 = 0.f, a2 = 0.f, a3 = 0.f;
        #pragma unroll
        for (int r = 0; r < 3; ++r) {
            float4 ctr = *(float4*)&vs[r][c][4 + px0];
            float  lft = vs[r][c][3 + px0];
            float  rgt = vs[r][c][8 + px0];
            int r3 = r * 3;
            a0 = fmaf(w[0][r3], lft,   fmaf(w[0][r3+1], ctr.x, fmaf(w[0][r3+2], ctr.y, a0)));
            a1 = fmaf(w[1][r3], ctr.x, fmaf(w[1][r3+1], ctr.y, fmaf(w[1][r3+2], ctr.z, a1)));
            a2 = fmaf(w[2][r3], ctr.y, fmaf(w[2][r3+1], ctr.z, fmaf(w[2][r3+2], ctr.w, a2)));
            a3 = fmaf(w[3][r3], ctr.z, fmaf(w[3][r3+1], ctr.w, fmaf(w[3][r3+2], rgt,  a3)));
        }
        size_t base = ((size_t)b * CC + cb * 32 + c) * HW + h * WIMG + px0;
        float4 xa = *(const float4*)&x[base];
        float4 o;
        o.x = fmaf(g, a0, xa.x); o.y = fmaf(g, a1, xa.y);
        o.z = fmaf(g, a2, xa.z); o.w = fmaf(g, a3, xa.w);
        *(float4*)&out[base] = o;
    }
}

extern "C" void kernel_launch(void* const* d_in, const int* in_sizes, int n_in,
                              void* d_out, int out_size, void* d_ws, size_t ws_size,
                              hipStream_t stream)
{
    const float* x     = (const float*)d_in[0];
    const float* Wq    = (const float*)d_in[1];
    const float* bq    = (const float*)d_in[2];
    const float* Wk    = (const float*)d_in[3];
    const float* bk    = (const float*)d_in[4];
    const float* Wv    = (const float*)d_in[5];
    const float* bv    = (const float*)d_in[6];
    const float* gamma = (const float*)d_in[7];
    float* out = (float*)d_out;

    float* q  = (float*)d_ws;                                  //  4.19 MB
    float* k  = q + (size_t)B_ * CR * HW;                      //  4.19 MB
    unsigned short* vv = (unsigned short*)(k + (size_t)B_ * CR * HW); // 16.78 MB
    float* aw = (float*)(vv + (size_t)B_ * CC * HW);           //  1.57 MB
    unsigned short* Wb = (unsigned short*)(aw + (size_t)B_ * HW * 12); // 160 KB
    float* bb = (float*)(Wb + 320 * CC);

    wconv<<<dim3(320), 256, 0, stream>>>(Wq, bq, Wk, bk, Wv, bv, Wb, bb);
    proj_gemm<<<dim3(HW / 64, B_), 256, 0, stream>>>(Wb, bb, x, q, k, vv);
    attn_w<<<dim3(HIMG, B_), 256, 0, stream>>>(q, k, aw);
    apply<<<dim3(HIMG, CC / 32, B_), 256, 0, stream>>>(x, vv, aw, gamma, out);
}